// Round 6
// baseline (277.285 us; speedup 1.0000x reference)
//
#include <hip/hip_runtime.h>
#include <stdint.h>

#define HIDDEN 768
#define EMBED  512
#define BATCH  16
#define SEQ    512
#define NWORDS (BATCH*SEQ)      // 8192
#define PAD_FLAT_IDX 2047       // flat index of words[0, 511, 3]
#define NEG_SLOPE 0.1f

#define NBLK       512          // fused grid: co-resident by construction
#define XSEQ_BYTES 12582912
#define WT_BYTES   786432
#define CTR_OFF    (XSEQ_BYTES + WT_BYTES)   // 13369344, 64B-aligned

__device__ __forceinline__ unsigned short f2bf(float f) {
    unsigned int x = __float_as_uint(f);
    unsigned int r = x + 0x7fffu + ((x >> 16) & 1u);
    return (unsigned short)(r >> 16);
}

typedef __attribute__((ext_vector_type(8))) short bf16x8;
typedef __attribute__((ext_vector_type(4))) float f32x4;

__device__ __forceinline__ void load_lds16(const void* g, void* l) {
    __builtin_amdgcn_global_load_lds(
        (const __attribute__((address_space(1))) unsigned int*)g,
        (__attribute__((address_space(3))) unsigned int*)l,
        16, 0, 0);
}

#define BM 128
#define BN 64
#define BK 32
#define NSTEP (HIDDEN / BK)   // 24
#define NBUF 4

// ---------------------------------------------------------------------------
// FUSED kernel (R8, resubmitted): pool + wt-transpose + grid barrier + GEMM.
// Purpose: (a) remove a launch gap; (b) DIAGNOSTIC — if our work is the
// missing ~60-90us of the iteration, this kernel exceeds the ~55us top-5
// profile cutoff and its true duration becomes readable next round.
// Co-residency: __launch_bounds__(256,2) caps VGPR at 128; LDS 48.1KB ->
// >=2 blocks/CU -> all 512 blocks resident at dispatch (no deadlock).
// Barrier: release = __threadfence (drains stores, vmcnt(0)) + AGENT-scope
// fetch_add; acquire = AGENT-scope load spin. Failsafe spin cap converts
// any hang into a visible wrong answer.
// ---------------------------------------------------------------------------
__global__ __launch_bounds__(256, 2) void fused_kernel(
    const int* __restrict__ words, const float* __restrict__ w,
    const float* __restrict__ table, const float* __restrict__ bias,
    float* __restrict__ out, unsigned short* __restrict__ xseq,
    unsigned short* __restrict__ wt, unsigned int* __restrict__ ctr)
{
    __shared__ unsigned short sA[NBUF][BM * BK];   // 32 KB (gemm); aliased by transpose tile
    __shared__ unsigned short sB[NBUF][BN * BK];   // 16 KB
    __shared__ unsigned long long mask[8];

    int tid  = threadIdx.x;
    int bid  = blockIdx.x;                   // 0..511
    int wave = tid >> 6;
    int lane = tid & 63;

    // ================= phase 1: pool 16 words/block (4 per wave) =================
    {
        int b = bid >> 5;                    // batch 0..15
        int q = bid & 31;                    // block-within-batch
        int p0 = wave * 64 + lane, p1 = p0 + 256;
        int4 wa = ((const int4*)words)[b * SEQ + p0];
        int4 wb = ((const int4*)words)[b * SEQ + p1];
        unsigned long long mlo = __ballot((wa.x | wa.y | wa.z | wa.w) != 0);
        unsigned long long mhi = __ballot((wb.x | wb.y | wb.z | wb.w) != 0);
        if (lane == 0) { mask[wave] = mlo; mask[4 + wave] = mhi; }
        __syncthreads();

        int s0 = q * 16 + wave * 4;          // first of this wave's 4 words
        const int4* w4p = (const int4*)words + b * SEQ;
        int4 wv[4] = { w4p[s0], w4p[s0 + 1], w4p[s0 + 2], w4p[s0 + 3] };

        // 2-deep double-buffered gathers; loads unconditional (id==0 reads
        // table row 0, discarded by the accumulate guards — p(pad)~1/30522).
        float4 g[2][12];
#define PREFETCH(BUFI, V)                                                      \
        {                                                                      \
            const float4* r0 = (const float4*)(table + (size_t)(V).x * HIDDEN);\
            const float4* r1 = (const float4*)(table + (size_t)(V).y * HIDDEN);\
            const float4* r2 = (const float4*)(table + (size_t)(V).z * HIDDEN);\
            const float4* r3 = (const float4*)(table + (size_t)(V).w * HIDDEN);\
            g[BUFI][0] = r0[lane]; g[BUFI][1]  = r0[lane + 64]; g[BUFI][2]  = r0[lane + 128]; \
            g[BUFI][3] = r1[lane]; g[BUFI][4]  = r1[lane + 64]; g[BUFI][5]  = r1[lane + 128]; \
            g[BUFI][6] = r2[lane]; g[BUFI][7]  = r2[lane + 64]; g[BUFI][8]  = r2[lane + 128]; \
            g[BUFI][9] = r3[lane]; g[BUFI][10] = r3[lane + 64]; g[BUFI][11] = r3[lane + 128]; \
        }
        PREFETCH(0, wv[0])
#pragma unroll
        for (int j = 0; j < 4; ++j) {        // fully unrolled: all g[] indices static
            if (j < 3) {
                if (((j + 1) & 1) == 0) PREFETCH(0, wv[j + 1])
                else                    PREFETCH(1, wv[j + 1])
            }
            // dest row (stable compaction) for word s = s0+j
            int s = s0 + j;
            int seg = s >> 6, bit = s & 63;
            int vp = 0, tot = 0;
#pragma unroll
            for (int i = 0; i < 8; ++i) {
                unsigned long long m = mask[i];
                int c = __popcll(m);
                if (i < seg) vp += c;
                tot += c;
            }
            unsigned long long mseg = mask[seg];
            vp += __popcll(mseg & ((1ull << bit) - 1ull));
            bool valid = (mseg >> bit) & 1ull;
            int d = valid ? vp : (tot + (s - vp));
            int drow = b * SEQ + d;

            int4 v4 = wv[j];
            int cnt = (v4.x != 0) + (v4.y != 0) + (v4.z != 0) + (v4.w != 0);
            float sx[3] = {0.f,0.f,0.f}, sy[3] = {0.f,0.f,0.f};
            float sz[3] = {0.f,0.f,0.f}, sw[3] = {0.f,0.f,0.f};
            if (cnt == 0) {                  // ~never
                int pid = words[PAD_FLAT_IDX];
                const float4* rp = (const float4*)(table + (size_t)pid * HIDDEN);
#pragma unroll
                for (int c = 0; c < 3; ++c) {
                    float4 v = rp[lane + 64 * c];
                    sx[c] = v.x; sy[c] = v.y; sz[c] = v.z; sw[c] = v.w;
                }
                cnt = 1;
            } else {
                const float4* gg = (j & 1) ? g[1] : g[0];
#pragma unroll
                for (int c = 0; c < 3; ++c) {
                    if (v4.x) { sx[c] += gg[0+c].x; sy[c] += gg[0+c].y; sz[c] += gg[0+c].z; sw[c] += gg[0+c].w; }
                    if (v4.y) { sx[c] += gg[3+c].x; sy[c] += gg[3+c].y; sz[c] += gg[3+c].z; sw[c] += gg[3+c].w; }
                    if (v4.z) { sx[c] += gg[6+c].x; sy[c] += gg[6+c].y; sz[c] += gg[6+c].z; sw[c] += gg[6+c].w; }
                    if (v4.w) { sx[c] += gg[9+c].x; sy[c] += gg[9+c].y; sz[c] += gg[9+c].z; sw[c] += gg[9+c].w; }
                }
            }
            float inv = 1.0f / (float)cnt;
#pragma unroll
            for (int c = 0; c < 3; ++c) {
                ushort4 o;
                o.x = f2bf(sx[c] * inv); o.y = f2bf(sy[c] * inv);
                o.z = f2bf(sz[c] * inv); o.w = f2bf(sw[c] * inv);
                *(ushort4*)&xseq[(size_t)drow * HIDDEN + (lane + 64 * c) * 4] = o;
            }
        }
#undef PREFETCH
    }

    // ====== phase 1b: wt transpose, blocks 0..383 (tile aliases sA; gemm ======
    // ====== touches sA only after the grid barrier -> no race)          ======
    if (bid < 384) {                          // block-uniform branch: barriers legal
        float (*tile)[33] = (float (*)[33])(&sA[0][0]);   // 4224 B < 8 KB
        int k0 = (bid % (HIDDEN / 32)) * 32;
        int n0 = (bid / (HIDDEN / 32)) * 32;
        int tc = tid & 31;
        int tr = tid >> 5;
#pragma unroll
        for (int i = 0; i < 4; ++i) {
            int r = tr + i * 8;
            tile[r][tc] = w[(size_t)(k0 + r) * EMBED + n0 + tc];
        }
        __syncthreads();
#pragma unroll
        for (int i = 0; i < 4; ++i) {
            int r = tr + i * 8;
            wt[(size_t)(n0 + r) * HIDDEN + k0 + tc] = f2bf(tile[tc][r]);
        }
    }

    // ================= grid barrier (release -> arrive -> acquire) =================
    __threadfence();                          // drain xseq/wt stores, device scope
    __syncthreads();
    if (tid == 0) {
        __hip_atomic_fetch_add(ctr, 1u, __ATOMIC_ACQ_REL, __HIP_MEMORY_SCOPE_AGENT);
        long long spin = 0;
        while (__hip_atomic_load(ctr, __ATOMIC_ACQUIRE, __HIP_MEMORY_SCOPE_AGENT) < NBLK) {
            if (++spin > (1ll << 22)) break;  // failsafe: hang -> visible wrong answer
        }
    }
    __syncthreads();

    // ================= phase 2: GEMM (R6-verbatim body) =================
    {
        int swz = (bid & 7) * 64 + (bid >> 3);   // XCD-chunked, bijective
        int m0  = (swz >> 3) * BM;
        int n0  = (swz & 7) * BN;
        int wr  = wave >> 1;
        int wc  = wave & 1;
        int quad = lane >> 4;
        int l16  = lane & 15;

        f32x4 acc[4][2] = {};

        const unsigned short* ga0 = xseq + (size_t)(m0 + (tid >> 2)) * HIDDEN + (tid & 3) * 8;
        const unsigned short* ga1 = xseq + (size_t)(m0 + 64 + (tid >> 2)) * HIDDEN + (tid & 3) * 8;
        const unsigned short* gb  = wt   + (size_t)(n0 + (tid >> 2)) * HIDDEN + (tid & 3) * 8;

        load_lds16(ga0,      &sA[0][tid * 8]);
        load_lds16(ga1,      &sA[0][(256 + tid) * 8]);
        load_lds16(gb,       &sB[0][tid * 8]);
        load_lds16(ga0 + BK, &sA[1][tid * 8]);
        load_lds16(ga1 + BK, &sA[1][(256 + tid) * 8]);
        load_lds16(gb  + BK, &sB[1][tid * 8]);

#pragma unroll
        for (int t = 0; t < NSTEP; ++t) {
            if (t + 2 < NSTEP) {
                const int k0  = (t + 2) * BK;
                const int buf = (t + 2) & (NBUF - 1);
                load_lds16(ga0 + k0, &sA[buf][tid * 8]);
                load_lds16(ga1 + k0, &sA[buf][(256 + tid) * 8]);
                load_lds16(gb  + k0, &sB[buf][tid * 8]);
            }
            if (t < NSTEP - 2)
                asm volatile("s_waitcnt vmcnt(6)\n\ts_barrier" ::: "memory");
            else if (t == NSTEP - 2)
                asm volatile("s_waitcnt vmcnt(3)\n\ts_barrier" ::: "memory");
            else
                asm volatile("s_waitcnt vmcnt(0)\n\ts_barrier" ::: "memory");

            const int buf = t & (NBUF - 1);
            bf16x8 af[4], bfr[2];
#pragma unroll
            for (int mt = 0; mt < 4; ++mt)
                af[mt] = *(const bf16x8*)&sA[buf][(wr * 64 + mt * 16 + l16) * BK + quad * 8];
#pragma unroll
            for (int nt = 0; nt < 2; ++nt)
                bfr[nt] = *(const bf16x8*)&sB[buf][(wc * 32 + nt * 16 + l16) * BK + quad * 8];

#pragma unroll
            for (int mt = 0; mt < 4; ++mt)
#pragma unroll
                for (int nt = 0; nt < 2; ++nt)
                    acc[mt][nt] = __builtin_amdgcn_mfma_f32_16x16x32_bf16(
                        af[mt], bfr[nt], acc[mt][nt], 0, 0, 0);
        }

#pragma unroll
        for (int nt = 0; nt < 2; ++nt) {
            int col = n0 + wc * 32 + nt * 16 + l16;
            float bv = bias[col];
#pragma unroll
            for (int mt = 0; mt < 4; ++mt) {
                int rbase = m0 + wr * 64 + mt * 16 + quad * 4;
#pragma unroll
                for (int r = 0; r < 4; ++r) {
                    float v = acc[mt][nt][r] + bv;
                    v = (v > 0.f) ? v : v * NEG_SLOPE;
                    out[(size_t)(rbase + r) * EMBED + col] = v;
                }
            }
        }
    }
}

// ---------------------------------------------------------------------------
extern "C" void kernel_launch(void* const* d_in, const int* in_sizes, int n_in,
                              void* d_out, int out_size, void* d_ws, size_t ws_size,
                              hipStream_t stream) {
    (void)in_sizes; (void)n_in; (void)out_size; (void)ws_size;
    const int*   words = (const int*)d_in[0];
    const float* table = (const float*)d_in[1];
    const float* wffn  = (const float*)d_in[2];
    const float* bffn  = (const float*)d_in[3];
    float* out = (float*)d_out;

    char* ws = (char*)d_ws;
    unsigned short* xseq = (unsigned short*)ws;
    unsigned short* wt   = (unsigned short*)(ws + XSEQ_BYTES);
    unsigned int*   ctr  = (unsigned int*)(ws + CTR_OFF);

    // workspace poison is a non-zero pattern -> zero the arrival counter
    hipMemsetAsync(ctr, 0, 64, stream);
    fused_kernel<<<NBLK, 256, 0, stream>>>(words, wffn, table, bffn, out, xseq, wt, ctr);
}

// Round 7
// 160.267 us; speedup vs baseline: 1.7301x; 1.7301x over previous
//
#include <hip/hip_runtime.h>
#include <stdint.h>

#define HIDDEN 768
#define EMBED  512
#define BATCH  16
#define SEQ    512
#define NWORDS (BATCH*SEQ)      // 8192
#define PAD_FLAT_IDX 2047       // flat index of words[0, 511, 3]
#define NEG_SLOPE 0.1f
#define NPOOLBLK 2048           // 4 words per block, 128 blocks per batch

__device__ __forceinline__ unsigned short f2bf(float f) {
    unsigned int x = __float_as_uint(f);
    unsigned int r = x + 0x7fffu + ((x >> 16) & 1u);
    return (unsigned short)(r >> 16);
}

// ---------------------------------------------------------------------------
// Kernel 1 (combo): blocks 0..2047 -> pool 4 words each (one per wave).
// R9 = REVERT to R7 (best measured: 160.6/161.9 us). R8 fusion regressed to
// 277 us (168 us fused dispatch, all pipes idle): grid-barrier agent-scope
// acquire/release (L2 invalidate + writeback storms) + low-TLP pool phase.
// High-TLP two-kernel structure restored verbatim.
// ---------------------------------------------------------------------------
__global__ __launch_bounds__(256) void combo_kernel(const int* __restrict__ words,
                                                    const float* __restrict__ w,
                                                    const float* __restrict__ table,
                                                    unsigned short* __restrict__ xseq,
                                                    unsigned short* __restrict__ wt) {
    if (blockIdx.x < NPOOLBLK) {
        __shared__ unsigned long long mask[8];   // validity bits, seg i = words 64i..64i+63
        int b    = blockIdx.x >> 7;              // batch
        int wave = threadIdx.x >> 6;
        int lane = threadIdx.x & 63;
        int s    = (blockIdx.x & 127) * 4 + wave;   // wave-uniform word index

        // ---- issue ALL independent loads first (wa, wb, w4 — one wait) ----
        int p0 = wave * 64 + lane;               // 0..255
        int p1 = p0 + 256;                       // 256..511
        int4 wa = ((const int4*)words)[b * SEQ + p0];
        int4 wb = ((const int4*)words)[b * SEQ + p1];
        int4 w4 = ((const int4*)words)[b * SEQ + s];

        // ---- issue the 12 gather loads (depend only on w4) ----
        int id0 = w4.x, id1 = w4.y, id2 = w4.z, id3 = w4.w;
        float4 g0[3], g1[3], g2[3], g3[3];
        if (id0) { const float4* rp = (const float4*)(table + (size_t)id0 * HIDDEN);
            g0[0] = rp[lane]; g0[1] = rp[lane + 64]; g0[2] = rp[lane + 128]; }
        if (id1) { const float4* rp = (const float4*)(table + (size_t)id1 * HIDDEN);
            g1[0] = rp[lane]; g1[1] = rp[lane + 64]; g1[2] = rp[lane + 128]; }
        if (id2) { const float4* rp = (const float4*)(table + (size_t)id2 * HIDDEN);
            g2[0] = rp[lane]; g2[1] = rp[lane + 64]; g2[2] = rp[lane + 128]; }
        if (id3) { const float4* rp = (const float4*)(table + (size_t)id3 * HIDDEN);
            g3[0] = rp[lane]; g3[1] = rp[lane + 64]; g3[2] = rp[lane + 128]; }

        // ---- mask phase (independent of gathers; overlaps their latency) ----
        unsigned long long mlo = __ballot((wa.x | wa.y | wa.z | wa.w) != 0);
        unsigned long long mhi = __ballot((wb.x | wb.y | wb.z | wb.w) != 0);
        if (lane == 0) { mask[wave] = mlo; mask[4 + wave] = mhi; }
        __syncthreads();

        int seg = s >> 6;
        int bit = s & 63;
        int vp = 0, tot = 0;
#pragma unroll
        for (int i = 0; i < 8; ++i) {
            unsigned long long m = mask[i];
            int c = __popcll(m);
            if (i < seg) vp += c;
            tot += c;
        }
        unsigned long long mseg = mask[seg];
        vp += __popcll(mseg & ((1ull << bit) - 1ull));
        bool valid = (mseg >> bit) & 1ull;
        int d = valid ? vp : (tot + (s - vp));   // stable; bijective over [0,SEQ)
        int drow = b * SEQ + d;

        // ---- accumulate (first consumption of gather data) ----
        int cnt = (id0 != 0) + (id1 != 0) + (id2 != 0) + (id3 != 0);
        float sx[3] = {0.f, 0.f, 0.f}, sy[3] = {0.f, 0.f, 0.f};
        float sz[3] = {0.f, 0.f, 0.f}, sw[3] = {0.f, 0.f, 0.f};
        if (cnt == 0) {                          // ~never (p ≈ 30522^-4)
            int pid = words[PAD_FLAT_IDX];
            const float4* rp = (const float4*)(table + (size_t)pid * HIDDEN);
#pragma unroll
            for (int c = 0; c < 3; ++c) {
                float4 v = rp[lane + 64 * c];
                sx[c] = v.x; sy[c] = v.y; sz[c] = v.z; sw[c] = v.w;
            }
            cnt = 1;
        } else {
#pragma unroll
            for (int c = 0; c < 3; ++c) {
                if (id0) { sx[c] += g0[c].x; sy[c] += g0[c].y; sz[c] += g0[c].z; sw[c] += g0[c].w; }
                if (id1) { sx[c] += g1[c].x; sy[c] += g1[c].y; sz[c] += g1[c].z; sw[c] += g1[c].w; }
                if (id2) { sx[c] += g2[c].x; sy[c] += g2[c].y; sz[c] += g2[c].z; sw[c] += g2[c].w; }
                if (id3) { sx[c] += g3[c].x; sy[c] += g3[c].y; sz[c] += g3[c].z; sw[c] += g3[c].w; }
            }
        }
        float inv = 1.0f / (float)cnt;
#pragma unroll
        for (int c = 0; c < 3; ++c) {
            ushort4 o;
            o.x = f2bf(sx[c] * inv); o.y = f2bf(sy[c] * inv);
            o.z = f2bf(sz[c] * inv); o.w = f2bf(sw[c] * inv);
            *(ushort4*)&xseq[(size_t)drow * HIDDEN + (lane + 64 * c) * 4] = o;
        }
    } else {
        // ---- transpose+downcast w[k][n] -> wt[n][k] (R2-verbatim) ----
        __shared__ float tile[32][33];
        int bid = blockIdx.x - NPOOLBLK;        // 0..383
        int k0 = (bid % (HIDDEN / 32)) * 32;
        int n0 = (bid / (HIDDEN / 32)) * 32;
        int tc = threadIdx.x & 31;
        int tr = threadIdx.x >> 5;              // 0..7
#pragma unroll
        for (int i = 0; i < 4; ++i) {
            int r = tr + i * 8;
            tile[r][tc] = w[(size_t)(k0 + r) * EMBED + n0 + tc];
        }
        __syncthreads();
#pragma unroll
        for (int i = 0; i < 4; ++i) {
            int r = tr + i * 8;                 // n offset within tile
            wt[(size_t)(n0 + r) * HIDDEN + k0 + tc] = f2bf(tile[tc][r]);
        }
    }
}

// ---------------------------------------------------------------------------
// Kernel 2: GEMM, C = leaky_relu(A @ Bt^T + bias). R6-verbatim (measured
// correct + neutral). Counted-vmcnt 4-buffer pipeline + bijective
// XCD-chunked swizzle.
// ---------------------------------------------------------------------------
typedef __attribute__((ext_vector_type(8))) short bf16x8;
typedef __attribute__((ext_vector_type(4))) float f32x4;

__device__ __forceinline__ void load_lds16(const void* g, void* l) {
    __builtin_amdgcn_global_load_lds(
        (const __attribute__((address_space(1))) unsigned int*)g,
        (__attribute__((address_space(3))) unsigned int*)l,
        16, 0, 0);
}

#define BM 128
#define BN 64
#define BK 32
#define NSTEP (HIDDEN / BK)   // 24
#define NBUF 4

__global__ __launch_bounds__(256) void gemm_kernel(const unsigned short* __restrict__ A,
                                                   const unsigned short* __restrict__ Bt,
                                                   const float* __restrict__ bias,
                                                   float* __restrict__ out) {
    __shared__ unsigned short sA[NBUF][BM * BK];   // 4 x 8 KB
    __shared__ unsigned short sB[NBUF][BN * BK];   // 4 x 4 KB

    int tid = threadIdx.x;
    int bid = blockIdx.x;                    // 0..511
    int swz = (bid & 7) * 64 + (bid >> 3);   // XCD-chunked, bijective (512%8==0)
    int m0  = (swz >> 3) * BM;               // n-fastest logical order
    int n0  = (swz & 7) * BN;
    int wave = tid >> 6;
    int lane = tid & 63;
    int wr   = wave >> 1;        // 0..1: 64-row slab
    int wc   = wave & 1;         // 0..1: 32-col slab
    int quad = lane >> 4;        // 0..3
    int l16  = lane & 15;

    f32x4 acc[4][2] = {};

    const unsigned short* ga0 = A  + (size_t)(m0 + (tid >> 2)) * HIDDEN + (tid & 3) * 8;
    const unsigned short* ga1 = A  + (size_t)(m0 + 64 + (tid >> 2)) * HIDDEN + (tid & 3) * 8;
    const unsigned short* gb  = Bt + (size_t)(n0 + (tid >> 2)) * HIDDEN + (tid & 3) * 8;

    // prologue: stage steps 0 and 1
    load_lds16(ga0,      &sA[0][tid * 8]);
    load_lds16(ga1,      &sA[0][(256 + tid) * 8]);
    load_lds16(gb,       &sB[0][tid * 8]);
    load_lds16(ga0 + BK, &sA[1][tid * 8]);
    load_lds16(ga1 + BK, &sA[1][(256 + tid) * 8]);
    load_lds16(gb  + BK, &sB[1][tid * 8]);

#pragma unroll
    for (int t = 0; t < NSTEP; ++t) {
        if (t + 2 < NSTEP) {                 // stage step t+2 (compile-time after unroll)
            const int k0  = (t + 2) * BK;
            const int buf = (t + 2) & (NBUF - 1);
            load_lds16(ga0 + k0, &sA[buf][tid * 8]);
            load_lds16(ga1 + k0, &sA[buf][(256 + tid) * 8]);
            load_lds16(gb  + k0, &sB[buf][tid * 8]);
        }
        // counted wait: step t's 3 loads are the oldest; 6 (steps t+1,t+2)
        // may stay in flight across the barrier. Tail: 3, then 0.
        if (t < NSTEP - 2)
            asm volatile("s_waitcnt vmcnt(6)\n\ts_barrier" ::: "memory");
        else if (t == NSTEP - 2)
            asm volatile("s_waitcnt vmcnt(3)\n\ts_barrier" ::: "memory");
        else
            asm volatile("s_waitcnt vmcnt(0)\n\ts_barrier" ::: "memory");

        const int buf = t & (NBUF - 1);
        bf16x8 af[4], bfr[2];
#pragma unroll
        for (int mt = 0; mt < 4; ++mt)
            af[mt] = *(const bf16x8*)&sA[buf][(wr * 64 + mt * 16 + l16) * BK + quad * 8];
#pragma unroll
        for (int nt = 0; nt < 2; ++nt)
            bfr[nt] = *(const bf16x8*)&sB[buf][(wc * 32 + nt * 16 + l16) * BK + quad * 8];

#pragma unroll
        for (int mt = 0; mt < 4; ++mt)
#pragma unroll
            for (int nt = 0; nt < 2; ++nt)
                acc[mt][nt] = __builtin_amdgcn_mfma_f32_16x16x32_bf16(
                    af[mt], bfr[nt], acc[mt][nt], 0, 0, 0);
    }

    // epilogue: D row = quad*4+r, col = l16 (verified layout, rounds 1-5)
#pragma unroll
    for (int nt = 0; nt < 2; ++nt) {
        int col = n0 + wc * 32 + nt * 16 + l16;
        float bv = bias[col];
#pragma unroll
        for (int mt = 0; mt < 4; ++mt) {
            int rbase = m0 + wr * 64 + mt * 16 + quad * 4;
#pragma unroll
            for (int r = 0; r < 4; ++r) {
                float v = acc[mt][nt][r] + bv;
                v = (v > 0.f) ? v : v * NEG_SLOPE;
                out[(size_t)(rbase + r) * EMBED + col] = v;
            }
        }
    }
}

// ---------------------------------------------------------------------------
extern "C" void kernel_launch(void* const* d_in, const int* in_sizes, int n_in,
                              void* d_out, int out_size, void* d_ws, size_t ws_size,
                              hipStream_t stream) {
    (void)in_sizes; (void)n_in; (void)out_size; (void)ws_size;
    const int*   words = (const int*)d_in[0];
    const float* table = (const float*)d_in[1];
    const float* wffn  = (const float*)d_in[2];
    const float* bffn  = (const float*)d_in[3];
    float* out = (float*)d_out;

    char* ws = (char*)d_ws;
    unsigned short* xseq = (unsigned short*)ws;                       // 12582912 B
    unsigned short* wt   = (unsigned short*)(ws + 12582912);          //   786432 B

    combo_kernel<<<NPOOLBLK + (HIDDEN / 32) * (EMBED / 32), 256, 0, stream>>>(
        words, wffn, table, xseq, wt);
    gemm_kernel<<<NWORDS / BM * (EMBED / BN), 256, 0, stream>>>(xseq, wt, bffn, out);
}